// Round 3
// baseline (5019.371 us; speedup 1.0000x reference)
//
#include <hip/hip_runtime.h>

// CRF forward chain on MI355X — linearized: u' = (1/g) diag(exp(h_s)) E u,
// E = exp(transitions) packed as f16 pairs (register-resident, 128 VGPR/lane).
// answer = C + log(sum_j exp(T[END,j]) u_j).
// R9: 16 chunks x 16 blocks x 1024 threads (16 waves, 128 rows/block)
// = 256 blocks = 1 block/CU GUARANTEED (the R6-proven residency regime).
// Critical path 1048 -> 536 dependent steps without any co-scheduling bet.
// Empirical launch_bounds semantics (R7/R8): 2nd arg = min BLOCKS/CU
// (CUDA-style): (512,4)->cap 64 (spilled), (512,2)->cap 128. Here (1024,1):
// 16 waves / 4 SIMD = 4 waves/SIMD -> cap 512/4 = 128 VGPR, exactly R6's tier.
// DATAFLOW SYNC as R6: sign-tagged u, poll IS the load; only WAVE 0 of each
// block polls; it normalizes + packs to f16 and broadcasts via LDS (4KB);
// other 15 waves pick up after one __syncthreads. Single barrier per step.
//
// ws floats: u_bufs[16][2][2048] @0, usave[16][2048] @65536,
// ufin[16][2048] @98304, cbuf[16] @131072 ; posts int[256*16] @byte 524544.

#define TSZ   2048
#define NCH   16
#define GBLK  16
#define NW    16
#define CH_LEN 512
#define BURN  24
#define START_I 0
#define END_I   1

typedef float v4f __attribute__((ext_vector_type(4)));
typedef _Float16 h2f __attribute__((ext_vector_type(2)));

__device__ __forceinline__ h2f pk16(float a, float b) {
    return __builtin_bit_cast(h2f, __builtin_amdgcn_cvt_pkrtz(a, b));
}
__device__ __forceinline__ void st_coh(float* p, float v) {
    asm volatile("global_store_dword %0, %1, off sc0 sc1"
                 :: "v"(p), "v"(v) : "memory");
}
__device__ __forceinline__ float ld_coh1(const float* p) {
    float r;
    asm volatile("global_load_dword %0, %1, off sc0 sc1\n\ts_waitcnt vmcnt(0)"
                 : "=&v"(r) : "v"(p) : "memory");
    return r;
}
__device__ __forceinline__ v4f ld_coh4(const float* p) {
    v4f r;
    asm volatile("global_load_dwordx4 %0, %1, off sc0 sc1\n\ts_waitcnt vmcnt(0)"
                 : "=&v"(r) : "v"(p) : "memory");
    return r;
}

__global__ __launch_bounds__(1024, 1)
void crf_chain(const float* __restrict__ h, const float* __restrict__ tr,
               float* __restrict__ out, float* __restrict__ ws)
{
    const int tid  = threadIdx.x;
    const int lane = tid & 63;
    const int wv   = tid >> 6;          // 0..15
    const int blk  = blockIdx.x;
    const int c    = blk >> 4;          // chunk id 0..15
    const int b    = blk & (GBLK - 1);  // block within chunk 0..15
    const int row_base = b * 128 + wv * 8;

    float* u_bufs = ws;                               // [NCH][2][TSZ]
    float* usave  = ws + NCH * 2 * TSZ;               // [NCH][TSZ]
    float* ufin   = usave + NCH * TSZ;                // [NCH][TSZ]
    float* cbuf   = ufin + NCH * TSZ;                 // [NCH]
    int*   posts  = (int*)((char*)ws + 524544);       // [256*16] per-wave completion

    // ---- one-time: E fragment, f16-pair packed. Lane covers cols 4*lane + 256*k + m.
    h2f e2[8][16];
    #pragma unroll
    for (int r = 0; r < 8; ++r) {
        const float* trow = tr + (size_t)(row_base + r) * TSZ + 4 * lane;
        #pragma unroll
        for (int k = 0; k < 8; ++k) {
            float4 t4 = *(const float4*)(trow + 256 * k);
            e2[r][2 * k]     = pk16(__expf(t4.x), __expf(t4.y));
            e2[r][2 * k + 1] = pk16(__expf(t4.z), __expf(t4.w));
        }
    }

    const int s_keep  = c * CH_LEN;
    const int s_begin = (c == 0) ? 0 : (s_keep - BURN);
    const int s_end   = s_keep + CH_LEN;
    const int T_iter  = s_end - s_begin;

    const int q    = ((lane & 1) << 2) | (lane & 2) | ((lane >> 2) & 1);
    const int grow = row_base + q;

    __shared__ unsigned long long uh_sh[512];   // 2048 normalized f16 values

    // ---- init: u^0 into buf parity 0, POSITIVE tag (poison 0xAA.. is negative)
    if (tid < 128) {
        int row = b * 128 + tid;
        float v = (c == 0) ? ((row == START_I) ? 1.0f : 0.0f) : 1.0f;
        st_coh(&u_bufs[(c * 2 + 0) * TSZ + row], v);
    }

    float Chat = 0.0f;

    for (int t = 0; t < T_iter; ++t) {
        const int s = s_begin + t;
        float* u_out = u_bufs + (c * 2 + ((t + 1) & 1)) * TSZ;
        const int out_neg = ((t + 1) >> 1) & 1;    // tag we write

        // prefetch emission (plain cached load) to overlap the wait
        float hv = 0.0f;
        if (lane < 8) hv = h[(size_t)s * TSZ + grow];

        if (wv == 0) {
            const float* u_in = u_bufs + (c * 2 + (t & 1)) * TSZ;
            const int in_neg  = (t >> 1) & 1;      // expected tag of u_in

            // ---- poll-by-load: re-load until every value carries the expected sign
            v4f u0, u1, u2, u3, u4, u5, u6, u7;
            const float* pa = u_in + 4 * lane;       // k=0..3
            const float* pb = pa + 1024;             // k=4..7
            for (;;) {
                asm volatile(
                    "global_load_dwordx4 %0, %8, off sc0 sc1\n\t"
                    "global_load_dwordx4 %1, %8, off offset:1024 sc0 sc1\n\t"
                    "global_load_dwordx4 %2, %8, off offset:2048 sc0 sc1\n\t"
                    "global_load_dwordx4 %3, %8, off offset:3072 sc0 sc1\n\t"
                    "global_load_dwordx4 %4, %9, off sc0 sc1\n\t"
                    "global_load_dwordx4 %5, %9, off offset:1024 sc0 sc1\n\t"
                    "global_load_dwordx4 %6, %9, off offset:2048 sc0 sc1\n\t"
                    "global_load_dwordx4 %7, %9, off offset:3072 sc0 sc1\n\t"
                    "s_waitcnt vmcnt(0)"
                    : "=&v"(u0), "=&v"(u1), "=&v"(u2), "=&v"(u3),
                      "=&v"(u4), "=&v"(u5), "=&v"(u6), "=&v"(u7)
                    : "v"(pa), "v"(pb)
                    : "memory");
                bool fresh;
                if (in_neg) {
                    int a = __float_as_int(u0.x) & __float_as_int(u0.y) & __float_as_int(u0.z) & __float_as_int(u0.w);
                    a &= __float_as_int(u1.x) & __float_as_int(u1.y) & __float_as_int(u1.z) & __float_as_int(u1.w);
                    a &= __float_as_int(u2.x) & __float_as_int(u2.y) & __float_as_int(u2.z) & __float_as_int(u2.w);
                    a &= __float_as_int(u3.x) & __float_as_int(u3.y) & __float_as_int(u3.z) & __float_as_int(u3.w);
                    a &= __float_as_int(u4.x) & __float_as_int(u4.y) & __float_as_int(u4.z) & __float_as_int(u4.w);
                    a &= __float_as_int(u5.x) & __float_as_int(u5.y) & __float_as_int(u5.z) & __float_as_int(u5.w);
                    a &= __float_as_int(u6.x) & __float_as_int(u6.y) & __float_as_int(u6.z) & __float_as_int(u6.w);
                    a &= __float_as_int(u7.x) & __float_as_int(u7.y) & __float_as_int(u7.z) & __float_as_int(u7.w);
                    fresh = (a < 0);                   // all sign bits set
                } else {
                    int o = __float_as_int(u0.x) | __float_as_int(u0.y) | __float_as_int(u0.z) | __float_as_int(u0.w);
                    o |= __float_as_int(u1.x) | __float_as_int(u1.y) | __float_as_int(u1.z) | __float_as_int(u1.w);
                    o |= __float_as_int(u2.x) | __float_as_int(u2.y) | __float_as_int(u2.z) | __float_as_int(u2.w);
                    o |= __float_as_int(u3.x) | __float_as_int(u3.y) | __float_as_int(u3.z) | __float_as_int(u3.w);
                    o |= __float_as_int(u4.x) | __float_as_int(u4.y) | __float_as_int(u4.z) | __float_as_int(u4.w);
                    o |= __float_as_int(u5.x) | __float_as_int(u5.y) | __float_as_int(u5.z) | __float_as_int(u5.w);
                    o |= __float_as_int(u6.x) | __float_as_int(u6.y) | __float_as_int(u6.z) | __float_as_int(u6.w);
                    o |= __float_as_int(u7.x) | __float_as_int(u7.y) | __float_as_int(u7.z) | __float_as_int(u7.w);
                    fresh = (o >= 0);                  // all sign bits clear
                }
                if (__all(fresh)) break;
            }

            // ---- gmax = max |u_in| (bitwise-identical in every polling wave)
            float m;
            m =          fmaxf(fmaxf(fabsf(u0.x), fabsf(u0.y)), fmaxf(fabsf(u0.z), fabsf(u0.w)));
            m = fmaxf(m, fmaxf(fmaxf(fabsf(u1.x), fabsf(u1.y)), fmaxf(fabsf(u1.z), fabsf(u1.w))));
            m = fmaxf(m, fmaxf(fmaxf(fabsf(u2.x), fabsf(u2.y)), fmaxf(fabsf(u2.z), fabsf(u2.w))));
            m = fmaxf(m, fmaxf(fmaxf(fabsf(u3.x), fabsf(u3.y)), fmaxf(fabsf(u3.z), fabsf(u3.w))));
            m = fmaxf(m, fmaxf(fmaxf(fabsf(u4.x), fabsf(u4.y)), fmaxf(fabsf(u4.z), fabsf(u4.w))));
            m = fmaxf(m, fmaxf(fmaxf(fabsf(u5.x), fabsf(u5.y)), fmaxf(fabsf(u5.z), fabsf(u5.w))));
            m = fmaxf(m, fmaxf(fmaxf(fabsf(u6.x), fabsf(u6.y)), fmaxf(fabsf(u6.z), fabsf(u6.w))));
            m = fmaxf(m, fmaxf(fmaxf(fabsf(u7.x), fabsf(u7.y)), fmaxf(fabsf(u7.z), fabsf(u7.w))));
            #pragma unroll
            for (int d = 1; d < 64; d <<= 1) m = fmaxf(m, __shfl_xor(m, d, 64));

            // normalize (fold input sign), pack to f16, broadcast via LDS
            const float rn = (in_neg ? -1.0f : 1.0f) / m;
            h2f uh[16];
            uh[0]  = pk16(u0.x * rn, u0.y * rn);  uh[1]  = pk16(u0.z * rn, u0.w * rn);
            uh[2]  = pk16(u1.x * rn, u1.y * rn);  uh[3]  = pk16(u1.z * rn, u1.w * rn);
            uh[4]  = pk16(u2.x * rn, u2.y * rn);  uh[5]  = pk16(u2.z * rn, u2.w * rn);
            uh[6]  = pk16(u3.x * rn, u3.y * rn);  uh[7]  = pk16(u3.z * rn, u3.w * rn);
            uh[8]  = pk16(u4.x * rn, u4.y * rn);  uh[9]  = pk16(u4.z * rn, u4.w * rn);
            uh[10] = pk16(u5.x * rn, u5.y * rn);  uh[11] = pk16(u5.z * rn, u5.w * rn);
            uh[12] = pk16(u6.x * rn, u6.y * rn);  uh[13] = pk16(u6.z * rn, u6.w * rn);
            uh[14] = pk16(u7.x * rn, u7.y * rn);  uh[15] = pk16(u7.z * rn, u7.w * rn);
            #pragma unroll
            for (int k = 0; k < 8; ++k) {
                unsigned long long qw =
                    ((unsigned long long)__builtin_bit_cast(unsigned, uh[2 * k + 1]) << 32) |
                    (unsigned long long)__builtin_bit_cast(unsigned, uh[2 * k]);
                uh_sh[lane + 64 * k] = qw;
            }

            // log-scale accumulation for kept steps (m==1.0 at t==0 -> adds 0)
            if ((s + 1) > s_keep) Chat += __logf(m);
        }

        __syncthreads();   // LDS(t) ready; overwrite at t+1 is dataflow-safe

        // ---- all waves: unpack normalized u from LDS
        h2f uh[16];
        #pragma unroll
        for (int k = 0; k < 8; ++k) {
            unsigned long long qw = uh_sh[lane + 64 * k];
            uh[2 * k]     = __builtin_bit_cast(h2f, (unsigned)qw);
            uh[2 * k + 1] = __builtin_bit_cast(h2f, (unsigned)(qw >> 32));
        }

        // ---- GEMV via v_dot2_f32_f16: acc[r] = sum_j E[row_base+r][j] * u_norm[j]
        float acc[8];
        #pragma unroll
        for (int r = 0; r < 8; ++r) acc[r] = 0.0f;
        #pragma unroll
        for (int k = 0; k < 16; ++k) {
            #pragma unroll
            for (int r = 0; r < 8; ++r)
                acc[r] = __builtin_amdgcn_fdot2(e2[r][k], uh[k], acc[r], false);
        }

        // ---- multi-row butterfly: 8 rows x 64 lanes -> row q(lane), lanes 0..7
        #pragma unroll
        for (int r = 0; r < 4; ++r) {
            float send = (lane & 1) ? acc[r] : acc[r + 4];
            float recv = __shfl_xor(send, 1, 64);
            float keep = (lane & 1) ? acc[r + 4] : acc[r];
            acc[r] = keep + recv;
        }
        #pragma unroll
        for (int r = 0; r < 2; ++r) {
            float send = (lane & 2) ? acc[r] : acc[r + 2];
            float recv = __shfl_xor(send, 2, 64);
            float keep = (lane & 2) ? acc[r + 2] : acc[r];
            acc[r] = keep + recv;
        }
        {
            float send = (lane & 4) ? acc[0] : acc[1];
            float recv = __shfl_xor(send, 4, 64);
            float keep = (lane & 4) ? acc[1] : acc[0];
            acc[0] = keep + recv;
        }
        acc[0] += __shfl_xor(acc[0], 8, 64);
        acc[0] += __shfl_xor(acc[0], 16, 64);
        acc[0] += __shfl_xor(acc[0], 32, 64);

        if (lane < 8) {
            float ut = acc[0] * __expf(hv);        // true (positive) value
            st_coh(&u_out[grow], out_neg ? -ut : ut);
            if (c > 0 && (s + 1) == s_keep) st_coh(&usave[c * TSZ + grow], ut);
            if ((s + 1) == s_end)           st_coh(&ufin[c * TSZ + grow], ut);
        }
    }

    // ---- completion: ack all my stores at L3, then per-wave post
    if (b == 0 && wv == 0 && lane == 0) st_coh(&cbuf[c], Chat);
    asm volatile("s_waitcnt vmcnt(0)" ::: "memory");
    if (lane == 0)
        __hip_atomic_store(&posts[blk * NW + wv], 1,
                           __ATOMIC_RELAXED, __HIP_MEMORY_SCOPE_AGENT);

    // ---- finisher: chunk 0 / block 0 / wave 0 stitches chunks, writes scalar
    if (c == 0 && b == 0 && wv == 0) {
        int ok;
        do {
            __builtin_amdgcn_s_sleep(1);
            ok = 1;
            #pragma unroll
            for (int i = 0; i < 64; ++i) {
                int v = __hip_atomic_load(&posts[lane + 64 * i],
                                          __ATOMIC_RELAXED, __HIP_MEMORY_SCOPE_AGENT);
                ok &= (v == 1);
            }
        } while (!__all(ok));

        // stitch: match log(sum u) at chunk boundaries
        float O = 0.0f;
        for (int cc = 1; cc < NCH; ++cc) {
            float sa = 0.0f, sb = 0.0f;
            for (int j = 4 * lane; j < TSZ; j += 256) {
                v4f a4 = ld_coh4(&ufin[(cc - 1) * TSZ + j]);
                v4f b4 = ld_coh4(&usave[cc * TSZ + j]);
                sa += a4.x + a4.y + a4.z + a4.w;
                sb += b4.x + b4.y + b4.z + b4.w;
            }
            #pragma unroll
            for (int d = 1; d < 64; d <<= 1) {
                sa += __shfl_xor(sa, d, 64);
                sb += __shfl_xor(sb, d, 64);
            }
            O += ld_coh1(&cbuf[cc - 1]) + __logf(sa) - __logf(sb);
        }
        // terminal: O + C_last + log(sum_j exp(T[END,j]) u_j)
        float se = 0.0f;
        for (int j = 4 * lane; j < TSZ; j += 256) {
            const float4 t4 = *(const float4*)(tr + (size_t)END_I * TSZ + j);
            v4f uf = ld_coh4(&ufin[(NCH - 1) * TSZ + j]);
            se += __expf(t4.x) * uf.x + __expf(t4.y) * uf.y +
                  __expf(t4.z) * uf.z + __expf(t4.w) * uf.w;
        }
        #pragma unroll
        for (int d = 1; d < 64; d <<= 1) se += __shfl_xor(se, d, 64);

        float ans = O + ld_coh1(&cbuf[NCH - 1]) + __logf(se);
        if (lane == 0) out[0] = ans;
    }
}

extern "C" void kernel_launch(void* const* d_in, const int* in_sizes, int n_in,
                              void* d_out, int out_size, void* d_ws, size_t ws_size,
                              hipStream_t stream) {
    const float* h  = (const float*)d_in[0];   // [8192, 2048] fp32 emissions
    const float* tr = (const float*)d_in[1];   // [2048, 2048] fp32 transitions
    (void)in_sizes; (void)n_in; (void)out_size; (void)ws_size;
    crf_chain<<<dim3(NCH * GBLK), dim3(1024), 0, stream>>>(h, tr, (float*)d_out, (float*)d_ws);
}

// Round 4
// 2226.836 us; speedup vs baseline: 2.2540x; 2.2540x over previous
//
#include <hip/hip_runtime.h>

// CRF forward chain on MI355X — linearized: u' = (1/g) diag(exp(h_s)) E u.
// R10: 128 rows/block at the 2-waves/SIMD (256-reg) tier.
// Unified-VGPR model fitted from R6-R9: true footprint ~176 regs/wave ->
// every config runs 2 waves/SIMD; >2 waves/SIMD spills (R7/R9). So: 512-thr
// blocks, 16 rows/wave = 12 rows in registers (e2r[12][16], 192 VGPR) +
// 4 rows in LDS (els64[32][512], 128KB; E is constant, written once).
// NCH=16 x GBLK=16 = 256 blocks = 1 block/CU (proven resident regime).
// Critical path 1048 -> 536 dependent steps. launch_bounds(512,1): empirical
// VGPR cap rule (512,1)->256, (512,2)->128, (512,4)->64.
// DATAFLOW SYNC as R6: sign-tagged u, poll IS the load; wave 0 polls,
// normalizes, packs f16, broadcasts via LDS; single __syncthreads per step.
//
// ws floats: u_bufs[16][2][2048] @0, usave[16][2048] @65536,
// ufin[16][2048] @98304, cbuf[16] @131072 ; posts int[2048] @byte 524544.

#define TSZ   2048
#define NCH   16
#define GBLK  16
#define NW    8
#define CH_LEN 512
#define BURN  24
#define START_I 0
#define END_I   1

typedef float v4f __attribute__((ext_vector_type(4)));
typedef _Float16 h2f __attribute__((ext_vector_type(2)));

__device__ __forceinline__ h2f pk16(float a, float b) {
    return __builtin_bit_cast(h2f, __builtin_amdgcn_cvt_pkrtz(a, b));
}
__device__ __forceinline__ void st_coh(float* p, float v) {
    asm volatile("global_store_dword %0, %1, off sc0 sc1"
                 :: "v"(p), "v"(v) : "memory");
}
__device__ __forceinline__ float ld_coh1(const float* p) {
    float r;
    asm volatile("global_load_dword %0, %1, off sc0 sc1\n\ts_waitcnt vmcnt(0)"
                 : "=&v"(r) : "v"(p) : "memory");
    return r;
}
__device__ __forceinline__ v4f ld_coh4(const float* p) {
    v4f r;
    asm volatile("global_load_dwordx4 %0, %1, off sc0 sc1\n\ts_waitcnt vmcnt(0)"
                 : "=&v"(r) : "v"(p) : "memory");
    return r;
}

__global__ __launch_bounds__(512, 1)
void crf_chain(const float* __restrict__ h, const float* __restrict__ tr,
               float* __restrict__ out, float* __restrict__ ws)
{
    const int tid  = threadIdx.x;
    const int lane = tid & 63;
    const int wv   = tid >> 6;          // 0..7
    const int blk  = blockIdx.x;
    const int c    = blk >> 4;          // chunk id 0..15
    const int b    = blk & (GBLK - 1);  // block within chunk 0..15
    const int row_base = b * 128 + wv * 16;

    float* u_bufs = ws;                               // [NCH][2][TSZ]
    float* usave  = ws + NCH * 2 * TSZ;               // [NCH][TSZ]
    float* ufin   = usave + NCH * TSZ;                // [NCH][TSZ]
    float* cbuf   = ufin + NCH * TSZ;                 // [NCH]
    int*   posts  = (int*)((char*)ws + 524544);       // [2048] per-wave completion

    // LDS: 4 E-rows per wave (rows row_base+12..15), f16-pair packed, 128KB,
    // written once. Plus 4KB broadcast buffer for normalized u.
    __shared__ unsigned long long els64[32][512];     // [wv*4+rr][lane + 64*k]
    __shared__ unsigned long long uh_sh[512];         // 2048 normalized f16

    // ---- one-time: register E fragment, 12 rows. Lane covers cols 4*lane+256*k.
    h2f e2r[12][16];
    #pragma unroll
    for (int r = 0; r < 12; ++r) {
        const float* trow = tr + (size_t)(row_base + r) * TSZ + 4 * lane;
        #pragma unroll
        for (int k = 0; k < 8; ++k) {
            float4 t4 = *(const float4*)(trow + 256 * k);
            e2r[r][2 * k]     = pk16(__expf(t4.x), __expf(t4.y));
            e2r[r][2 * k + 1] = pk16(__expf(t4.z), __expf(t4.w));
        }
    }
    // ---- one-time: LDS E rows 12..15 (same packing convention as uh_sh).
    #pragma unroll
    for (int rr = 0; rr < 4; ++rr) {
        const float* trow = tr + (size_t)(row_base + 12 + rr) * TSZ + 4 * lane;
        #pragma unroll
        for (int k = 0; k < 8; ++k) {
            float4 t4 = *(const float4*)(trow + 256 * k);
            unsigned lo = __builtin_bit_cast(unsigned, pk16(__expf(t4.x), __expf(t4.y)));
            unsigned hi = __builtin_bit_cast(unsigned, pk16(__expf(t4.z), __expf(t4.w)));
            els64[wv * 4 + rr][lane + 64 * k] =
                ((unsigned long long)hi << 32) | (unsigned long long)lo;
        }
    }

    const int s_keep  = c * CH_LEN;
    const int s_begin = (c == 0) ? 0 : (s_keep - BURN);
    const int s_end   = s_keep + CH_LEN;
    const int T_iter  = s_end - s_begin;

    const int q    = ((lane & 1) << 2) | (lane & 2) | ((lane >> 2) & 1);
    const int grow = row_base + q;          // rows grow and grow+8 per lane<8

    // ---- init: u^0 into buf parity 0, POSITIVE tag
    if (tid < 128) {
        int row = b * 128 + tid;
        float v = (c == 0) ? ((row == START_I) ? 1.0f : 0.0f) : 1.0f;
        st_coh(&u_bufs[(c * 2 + 0) * TSZ + row], v);
    }
    __syncthreads();   // els64 ready before first GEMV

    float Chat = 0.0f;

    for (int t = 0; t < T_iter; ++t) {
        const int s = s_begin + t;
        float* u_out = u_bufs + (c * 2 + ((t + 1) & 1)) * TSZ;
        const int out_neg = ((t + 1) >> 1) & 1;    // tag we write

        // prefetch emissions (plain cached loads) to overlap the wait
        float hv0 = 0.0f, hv1 = 0.0f;
        if (lane < 8) {
            hv0 = h[(size_t)s * TSZ + grow];
            hv1 = h[(size_t)s * TSZ + grow + 8];
        }

        if (wv == 0) {
            const float* u_in = u_bufs + (c * 2 + (t & 1)) * TSZ;
            const int in_neg  = (t >> 1) & 1;      // expected tag of u_in

            // ---- poll-by-load: re-load until every value carries the expected sign
            v4f u0, u1, u2, u3, u4, u5, u6, u7;
            const float* pa = u_in + 4 * lane;       // k=0..3
            const float* pb = pa + 1024;             // k=4..7
            for (;;) {
                asm volatile(
                    "global_load_dwordx4 %0, %8, off sc0 sc1\n\t"
                    "global_load_dwordx4 %1, %8, off offset:1024 sc0 sc1\n\t"
                    "global_load_dwordx4 %2, %8, off offset:2048 sc0 sc1\n\t"
                    "global_load_dwordx4 %3, %8, off offset:3072 sc0 sc1\n\t"
                    "global_load_dwordx4 %4, %9, off sc0 sc1\n\t"
                    "global_load_dwordx4 %5, %9, off offset:1024 sc0 sc1\n\t"
                    "global_load_dwordx4 %6, %9, off offset:2048 sc0 sc1\n\t"
                    "global_load_dwordx4 %7, %9, off offset:3072 sc0 sc1\n\t"
                    "s_waitcnt vmcnt(0)"
                    : "=&v"(u0), "=&v"(u1), "=&v"(u2), "=&v"(u3),
                      "=&v"(u4), "=&v"(u5), "=&v"(u6), "=&v"(u7)
                    : "v"(pa), "v"(pb)
                    : "memory");
                bool fresh;
                if (in_neg) {
                    int a = __float_as_int(u0.x) & __float_as_int(u0.y) & __float_as_int(u0.z) & __float_as_int(u0.w);
                    a &= __float_as_int(u1.x) & __float_as_int(u1.y) & __float_as_int(u1.z) & __float_as_int(u1.w);
                    a &= __float_as_int(u2.x) & __float_as_int(u2.y) & __float_as_int(u2.z) & __float_as_int(u2.w);
                    a &= __float_as_int(u3.x) & __float_as_int(u3.y) & __float_as_int(u3.z) & __float_as_int(u3.w);
                    a &= __float_as_int(u4.x) & __float_as_int(u4.y) & __float_as_int(u4.z) & __float_as_int(u4.w);
                    a &= __float_as_int(u5.x) & __float_as_int(u5.y) & __float_as_int(u5.z) & __float_as_int(u5.w);
                    a &= __float_as_int(u6.x) & __float_as_int(u6.y) & __float_as_int(u6.z) & __float_as_int(u6.w);
                    a &= __float_as_int(u7.x) & __float_as_int(u7.y) & __float_as_int(u7.z) & __float_as_int(u7.w);
                    fresh = (a < 0);                   // all sign bits set
                } else {
                    int o = __float_as_int(u0.x) | __float_as_int(u0.y) | __float_as_int(u0.z) | __float_as_int(u0.w);
                    o |= __float_as_int(u1.x) | __float_as_int(u1.y) | __float_as_int(u1.z) | __float_as_int(u1.w);
                    o |= __float_as_int(u2.x) | __float_as_int(u2.y) | __float_as_int(u2.z) | __float_as_int(u2.w);
                    o |= __float_as_int(u3.x) | __float_as_int(u3.y) | __float_as_int(u3.z) | __float_as_int(u3.w);
                    o |= __float_as_int(u4.x) | __float_as_int(u4.y) | __float_as_int(u4.z) | __float_as_int(u4.w);
                    o |= __float_as_int(u5.x) | __float_as_int(u5.y) | __float_as_int(u5.z) | __float_as_int(u5.w);
                    o |= __float_as_int(u6.x) | __float_as_int(u6.y) | __float_as_int(u6.z) | __float_as_int(u6.w);
                    o |= __float_as_int(u7.x) | __float_as_int(u7.y) | __float_as_int(u7.z) | __float_as_int(u7.w);
                    fresh = (o >= 0);                  // all sign bits clear
                }
                if (__all(fresh)) break;
            }

            // ---- gmax = max |u_in|
            float m;
            m =          fmaxf(fmaxf(fabsf(u0.x), fabsf(u0.y)), fmaxf(fabsf(u0.z), fabsf(u0.w)));
            m = fmaxf(m, fmaxf(fmaxf(fabsf(u1.x), fabsf(u1.y)), fmaxf(fabsf(u1.z), fabsf(u1.w))));
            m = fmaxf(m, fmaxf(fmaxf(fabsf(u2.x), fabsf(u2.y)), fmaxf(fabsf(u2.z), fabsf(u2.w))));
            m = fmaxf(m, fmaxf(fmaxf(fabsf(u3.x), fabsf(u3.y)), fmaxf(fabsf(u3.z), fabsf(u3.w))));
            m = fmaxf(m, fmaxf(fmaxf(fabsf(u4.x), fabsf(u4.y)), fmaxf(fabsf(u4.z), fabsf(u4.w))));
            m = fmaxf(m, fmaxf(fmaxf(fabsf(u5.x), fabsf(u5.y)), fmaxf(fabsf(u5.z), fabsf(u5.w))));
            m = fmaxf(m, fmaxf(fmaxf(fabsf(u6.x), fabsf(u6.y)), fmaxf(fabsf(u6.z), fabsf(u6.w))));
            m = fmaxf(m, fmaxf(fmaxf(fabsf(u7.x), fabsf(u7.y)), fmaxf(fabsf(u7.z), fabsf(u7.w))));
            #pragma unroll
            for (int d = 1; d < 64; d <<= 1) m = fmaxf(m, __shfl_xor(m, d, 64));

            // normalize (fold input sign), pack to f16, broadcast via LDS
            const float rn = (in_neg ? -1.0f : 1.0f) / m;
            h2f uh[16];
            uh[0]  = pk16(u0.x * rn, u0.y * rn);  uh[1]  = pk16(u0.z * rn, u0.w * rn);
            uh[2]  = pk16(u1.x * rn, u1.y * rn);  uh[3]  = pk16(u1.z * rn, u1.w * rn);
            uh[4]  = pk16(u2.x * rn, u2.y * rn);  uh[5]  = pk16(u2.z * rn, u2.w * rn);
            uh[6]  = pk16(u3.x * rn, u3.y * rn);  uh[7]  = pk16(u3.z * rn, u3.w * rn);
            uh[8]  = pk16(u4.x * rn, u4.y * rn);  uh[9]  = pk16(u4.z * rn, u4.w * rn);
            uh[10] = pk16(u5.x * rn, u5.y * rn);  uh[11] = pk16(u5.z * rn, u5.w * rn);
            uh[12] = pk16(u6.x * rn, u6.y * rn);  uh[13] = pk16(u6.z * rn, u6.w * rn);
            uh[14] = pk16(u7.x * rn, u7.y * rn);  uh[15] = pk16(u7.z * rn, u7.w * rn);
            #pragma unroll
            for (int k = 0; k < 8; ++k) {
                unsigned long long qw =
                    ((unsigned long long)__builtin_bit_cast(unsigned, uh[2 * k + 1]) << 32) |
                    (unsigned long long)__builtin_bit_cast(unsigned, uh[2 * k]);
                uh_sh[lane + 64 * k] = qw;
            }

            if ((s + 1) > s_keep) Chat += __logf(m);
        }

        __syncthreads();   // LDS(t) ready; overwrite at t+1 is dataflow-safe

        // ---- all waves: unpack normalized u from LDS
        h2f uh[16];
        #pragma unroll
        for (int k = 0; k < 8; ++k) {
            unsigned long long qw = uh_sh[lane + 64 * k];
            uh[2 * k]     = __builtin_bit_cast(h2f, (unsigned)qw);
            uh[2 * k + 1] = __builtin_bit_cast(h2f, (unsigned)(qw >> 32));
        }

        // ---- phase A: rows 0..7 (registers), butterfly -> resA
        float acc[8];
        #pragma unroll
        for (int r = 0; r < 8; ++r) acc[r] = 0.0f;
        #pragma unroll
        for (int k = 0; k < 16; ++k) {
            #pragma unroll
            for (int r = 0; r < 8; ++r)
                acc[r] = __builtin_amdgcn_fdot2(e2r[r][k], uh[k], acc[r], false);
        }
        #pragma unroll
        for (int r = 0; r < 4; ++r) {
            float send = (lane & 1) ? acc[r] : acc[r + 4];
            float recv = __shfl_xor(send, 1, 64);
            float keep = (lane & 1) ? acc[r + 4] : acc[r];
            acc[r] = keep + recv;
        }
        #pragma unroll
        for (int r = 0; r < 2; ++r) {
            float send = (lane & 2) ? acc[r] : acc[r + 2];
            float recv = __shfl_xor(send, 2, 64);
            float keep = (lane & 2) ? acc[r + 2] : acc[r];
            acc[r] = keep + recv;
        }
        {
            float send = (lane & 4) ? acc[0] : acc[1];
            float recv = __shfl_xor(send, 4, 64);
            float keep = (lane & 4) ? acc[1] : acc[0];
            acc[0] = keep + recv;
        }
        acc[0] += __shfl_xor(acc[0], 8, 64);
        acc[0] += __shfl_xor(acc[0], 16, 64);
        acc[0] += __shfl_xor(acc[0], 32, 64);
        float resA = acc[0];

        // ---- phase B: rows 8..11 (registers) + rows 12..15 (LDS), butterfly
        #pragma unroll
        for (int r = 0; r < 8; ++r) acc[r] = 0.0f;
        #pragma unroll
        for (int k = 0; k < 8; ++k) {       // k = b64 unit = h2f pair index
            unsigned long long q0 = els64[wv * 4 + 0][lane + 64 * k];
            unsigned long long q1 = els64[wv * 4 + 1][lane + 64 * k];
            unsigned long long q2 = els64[wv * 4 + 2][lane + 64 * k];
            unsigned long long q3 = els64[wv * 4 + 3][lane + 64 * k];
            #pragma unroll
            for (int r = 0; r < 4; ++r) {
                acc[r] = __builtin_amdgcn_fdot2(e2r[8 + r][2 * k],     uh[2 * k],     acc[r], false);
                acc[r] = __builtin_amdgcn_fdot2(e2r[8 + r][2 * k + 1], uh[2 * k + 1], acc[r], false);
            }
            acc[4] = __builtin_amdgcn_fdot2(__builtin_bit_cast(h2f, (unsigned)q0),         uh[2 * k],     acc[4], false);
            acc[4] = __builtin_amdgcn_fdot2(__builtin_bit_cast(h2f, (unsigned)(q0 >> 32)), uh[2 * k + 1], acc[4], false);
            acc[5] = __builtin_amdgcn_fdot2(__builtin_bit_cast(h2f, (unsigned)q1),         uh[2 * k],     acc[5], false);
            acc[5] = __builtin_amdgcn_fdot2(__builtin_bit_cast(h2f, (unsigned)(q1 >> 32)), uh[2 * k + 1], acc[5], false);
            acc[6] = __builtin_amdgcn_fdot2(__builtin_bit_cast(h2f, (unsigned)q2),         uh[2 * k],     acc[6], false);
            acc[6] = __builtin_amdgcn_fdot2(__builtin_bit_cast(h2f, (unsigned)(q2 >> 32)), uh[2 * k + 1], acc[6], false);
            acc[7] = __builtin_amdgcn_fdot2(__builtin_bit_cast(h2f, (unsigned)q3),         uh[2 * k],     acc[7], false);
            acc[7] = __builtin_amdgcn_fdot2(__builtin_bit_cast(h2f, (unsigned)(q3 >> 32)), uh[2 * k + 1], acc[7], false);
        }
        #pragma unroll
        for (int r = 0; r < 4; ++r) {
            float send = (lane & 1) ? acc[r] : acc[r + 4];
            float recv = __shfl_xor(send, 1, 64);
            float keep = (lane & 1) ? acc[r + 4] : acc[r];
            acc[r] = keep + recv;
        }
        #pragma unroll
        for (int r = 0; r < 2; ++r) {
            float send = (lane & 2) ? acc[r] : acc[r + 2];
            float recv = __shfl_xor(send, 2, 64);
            float keep = (lane & 2) ? acc[r + 2] : acc[r];
            acc[r] = keep + recv;
        }
        {
            float send = (lane & 4) ? acc[0] : acc[1];
            float recv = __shfl_xor(send, 4, 64);
            float keep = (lane & 4) ? acc[1] : acc[0];
            acc[0] = keep + recv;
        }
        acc[0] += __shfl_xor(acc[0], 8, 64);
        acc[0] += __shfl_xor(acc[0], 16, 64);
        acc[0] += __shfl_xor(acc[0], 32, 64);
        float resB = acc[0];

        if (lane < 8) {
            float utA = resA * __expf(hv0);        // row grow
            float utB = resB * __expf(hv1);        // row grow+8
            st_coh(&u_out[grow],     out_neg ? -utA : utA);
            st_coh(&u_out[grow + 8], out_neg ? -utB : utB);
            if (c > 0 && (s + 1) == s_keep) {
                st_coh(&usave[c * TSZ + grow],     utA);
                st_coh(&usave[c * TSZ + grow + 8], utB);
            }
            if ((s + 1) == s_end) {
                st_coh(&ufin[c * TSZ + grow],     utA);
                st_coh(&ufin[c * TSZ + grow + 8], utB);
            }
        }
    }

    // ---- completion: ack all my stores at L3, then per-wave post
    if (b == 0 && wv == 0 && lane == 0) st_coh(&cbuf[c], Chat);
    asm volatile("s_waitcnt vmcnt(0)" ::: "memory");
    if (lane == 0)
        __hip_atomic_store(&posts[blk * NW + wv], 1,
                           __ATOMIC_RELAXED, __HIP_MEMORY_SCOPE_AGENT);

    // ---- finisher: chunk 0 / block 0 / wave 0 stitches chunks, writes scalar
    if (c == 0 && b == 0 && wv == 0) {
        int ok;
        do {
            __builtin_amdgcn_s_sleep(1);
            ok = 1;
            #pragma unroll
            for (int i = 0; i < 32; ++i) {     // 256 blocks x 8 waves = 2048 posts
                int v = __hip_atomic_load(&posts[lane + 64 * i],
                                          __ATOMIC_RELAXED, __HIP_MEMORY_SCOPE_AGENT);
                ok &= (v == 1);
            }
        } while (!__all(ok));

        // stitch: match log(sum u) at chunk boundaries
        float O = 0.0f;
        for (int cc = 1; cc < NCH; ++cc) {
            float sa = 0.0f, sb = 0.0f;
            for (int j = 4 * lane; j < TSZ; j += 256) {
                v4f a4 = ld_coh4(&ufin[(cc - 1) * TSZ + j]);
                v4f b4 = ld_coh4(&usave[cc * TSZ + j]);
                sa += a4.x + a4.y + a4.z + a4.w;
                sb += b4.x + b4.y + b4.z + b4.w;
            }
            #pragma unroll
            for (int d = 1; d < 64; d <<= 1) {
                sa += __shfl_xor(sa, d, 64);
                sb += __shfl_xor(sb, d, 64);
            }
            O += ld_coh1(&cbuf[cc - 1]) + __logf(sa) - __logf(sb);
        }
        // terminal: O + C_last + log(sum_j exp(T[END,j]) u_j)
        float se = 0.0f;
        for (int j = 4 * lane; j < TSZ; j += 256) {
            const float4 t4 = *(const float4*)(tr + (size_t)END_I * TSZ + j);
            v4f uf = ld_coh4(&ufin[(NCH - 1) * TSZ + j]);
            se += __expf(t4.x) * uf.x + __expf(t4.y) * uf.y +
                  __expf(t4.z) * uf.z + __expf(t4.w) * uf.w;
        }
        #pragma unroll
        for (int d = 1; d < 64; d <<= 1) se += __shfl_xor(se, d, 64);

        float ans = O + ld_coh1(&cbuf[NCH - 1]) + __logf(se);
        if (lane == 0) out[0] = ans;
    }
}

extern "C" void kernel_launch(void* const* d_in, const int* in_sizes, int n_in,
                              void* d_out, int out_size, void* d_ws, size_t ws_size,
                              hipStream_t stream) {
    const float* h  = (const float*)d_in[0];   // [8192, 2048] fp32 emissions
    const float* tr = (const float*)d_in[1];   // [2048, 2048] fp32 transitions
    (void)in_sizes; (void)n_in; (void)out_size; (void)ws_size;
    crf_chain<<<dim3(NCH * GBLK), dim3(512), 0, stream>>>(h, tr, (float*)d_out, (float*)d_ws);
}

// Round 5
// 2084.039 us; speedup vs baseline: 2.4085x; 1.0685x over previous
//
#include <hip/hip_runtime.h>

// CRF forward chain on MI355X — linearized: u' = (1/g) diag(exp(h_s)) E u.
// R11: TWO-CHAIN INTERLEAVE. Each block owns chunks (cp, cp+16) sharing one
// E-slice (128 rows: 12 reg rows + 4 LDS rows per wave, as R10). While chain
// A's stores propagate (~1.5us device-scope visibility), the block computes
// chain B — visibility hides under compute. NCH=32, CH_LEN=256, BURN=24:
// critical path 536 -> 280 cycles (each cycle advances both chains 1 step).
// Grid 16 pairs x 16 blocks = 256 = 1 block/CU (proven resident regime).
// Poll duties split: wave0 polls A at end-of-cycle, wave1 polls B mid-cycle.
// Two barriers per cycle. Sign-tag/parity protocol per chain as R10.
//
// ws floats: u_bufs[32][2][2048] @0, usave[32][2048] @131072,
// ufin[32][2048] @196608, cbuf[32] @262144 ; posts int[2048] @byte 1048704.

#define TSZ   2048
#define NCH   32
#define GBLK  16
#define NW    8
#define CH_LEN 256
#define BURN  24
#define START_I 0
#define END_I   1

typedef float v4f __attribute__((ext_vector_type(4)));
typedef _Float16 h2f __attribute__((ext_vector_type(2)));

__device__ __forceinline__ h2f pk16(float a, float b) {
    return __builtin_bit_cast(h2f, __builtin_amdgcn_cvt_pkrtz(a, b));
}
__device__ __forceinline__ void st_coh(float* p, float v) {
    asm volatile("global_store_dword %0, %1, off sc0 sc1"
                 :: "v"(p), "v"(v) : "memory");
}
__device__ __forceinline__ float ld_coh1(const float* p) {
    float r;
    asm volatile("global_load_dword %0, %1, off sc0 sc1\n\ts_waitcnt vmcnt(0)"
                 : "=&v"(r) : "v"(p) : "memory");
    return r;
}
__device__ __forceinline__ v4f ld_coh4(const float* p) {
    v4f r;
    asm volatile("global_load_dwordx4 %0, %1, off sc0 sc1\n\ts_waitcnt vmcnt(0)"
                 : "=&v"(r) : "v"(p) : "memory");
    return r;
}

__global__ __launch_bounds__(512, 1)
void crf_chain(const float* __restrict__ h, const float* __restrict__ tr,
               float* __restrict__ out, float* __restrict__ ws)
{
    const int tid  = threadIdx.x;
    const int lane = tid & 63;
    const int wv   = tid >> 6;          // 0..7
    const int blk  = blockIdx.x;
    const int cp   = blk >> 4;          // pair id 0..15
    const int b    = blk & (GBLK - 1);  // block within pair 0..15
    const int ca   = cp;                // chain A chunk 0..15
    const int cb   = cp + 16;           // chain B chunk 16..31
    const int row_base = b * 128 + wv * 16;

    float* u_bufs = ws;                               // [NCH][2][TSZ]
    float* usave  = ws + NCH * 2 * TSZ;               // [NCH][TSZ]
    float* ufin   = usave + NCH * TSZ;                // [NCH][TSZ]
    float* cbuf   = ufin + NCH * TSZ;                 // [NCH]
    int*   posts  = (int*)((char*)ws + 1048704);      // [2048] per-wave completion

    // LDS: 4 E-rows per wave (rows row_base+12..15), f16-pair packed, 128KB,
    // written once; two 4KB broadcast buffers (one per chain).
    __shared__ unsigned long long els64[32][512];     // [wv*4+rr][lane + 64*k]
    __shared__ unsigned long long uh_shA[512];
    __shared__ unsigned long long uh_shB[512];

    // ---- one-time: register E fragment, 12 rows. Lane covers cols 4*lane+256*k.
    h2f e2r[12][16];
    #pragma unroll
    for (int r = 0; r < 12; ++r) {
        const float* trow = tr + (size_t)(row_base + r) * TSZ + 4 * lane;
        #pragma unroll
        for (int k = 0; k < 8; ++k) {
            float4 t4 = *(const float4*)(trow + 256 * k);
            e2r[r][2 * k]     = pk16(__expf(t4.x), __expf(t4.y));
            e2r[r][2 * k + 1] = pk16(__expf(t4.z), __expf(t4.w));
        }
    }
    // ---- one-time: LDS E rows 12..15 (same packing convention as uh_sh*).
    #pragma unroll
    for (int rr = 0; rr < 4; ++rr) {
        const float* trow = tr + (size_t)(row_base + 12 + rr) * TSZ + 4 * lane;
        #pragma unroll
        for (int k = 0; k < 8; ++k) {
            float4 t4 = *(const float4*)(trow + 256 * k);
            unsigned lo = __builtin_bit_cast(unsigned, pk16(__expf(t4.x), __expf(t4.y)));
            unsigned hi = __builtin_bit_cast(unsigned, pk16(__expf(t4.z), __expf(t4.w)));
            els64[wv * 4 + rr][lane + 64 * k] =
                ((unsigned long long)hi << 32) | (unsigned long long)lo;
        }
    }

    const int q    = ((lane & 1) << 2) | (lane & 2) | ((lane >> 2) & 1);
    const int grow = row_base + q;          // rows grow and grow+8 per lane<8

    // schedules: chunk 0 has no burn-in (true chain from one-hot)
    const int sA0 = (ca == 0) ? 0 : (ca * CH_LEN - BURN);
    const int TA  = (ca == 0) ? CH_LEN : (CH_LEN + BURN);
    const int skA = ca * CH_LEN, seA = skA + CH_LEN;
    const int sB0 = cb * CH_LEN - BURN;
    const int skB = cb * CH_LEN, seB = skB + CH_LEN;
    const int TB  = CH_LEN + BURN;          // loop bound (>= TA)

    // ---- init: u^0 for both chains into buf parity 0, POSITIVE tag
    if (tid < 128) {
        int row = b * 128 + tid;
        st_coh(&u_bufs[(ca * 2 + 0) * TSZ + row],
               (ca == 0) ? ((row == START_I) ? 1.0f : 0.0f) : 1.0f);
        st_coh(&u_bufs[(cb * 2 + 0) * TSZ + row], 1.0f);
    }
    __syncthreads();   // els64 ready

    float ChatA = 0.0f, ChatB = 0.0f;

    // ================= poll + normalize + pack into given LDS buffer ========
    auto POLL_PACK = [&](const float* u_in, int in_neg,
                         unsigned long long* uh_dst, float& Chat, bool kept) {
        v4f u0, u1, u2, u3, u4, u5, u6, u7;
        const float* pa = u_in + 4 * lane;       // k=0..3
        const float* pb = pa + 1024;             // k=4..7
        for (;;) {
            asm volatile(
                "global_load_dwordx4 %0, %8, off sc0 sc1\n\t"
                "global_load_dwordx4 %1, %8, off offset:1024 sc0 sc1\n\t"
                "global_load_dwordx4 %2, %8, off offset:2048 sc0 sc1\n\t"
                "global_load_dwordx4 %3, %8, off offset:3072 sc0 sc1\n\t"
                "global_load_dwordx4 %4, %9, off sc0 sc1\n\t"
                "global_load_dwordx4 %5, %9, off offset:1024 sc0 sc1\n\t"
                "global_load_dwordx4 %6, %9, off offset:2048 sc0 sc1\n\t"
                "global_load_dwordx4 %7, %9, off offset:3072 sc0 sc1\n\t"
                "s_waitcnt vmcnt(0)"
                : "=&v"(u0), "=&v"(u1), "=&v"(u2), "=&v"(u3),
                  "=&v"(u4), "=&v"(u5), "=&v"(u6), "=&v"(u7)
                : "v"(pa), "v"(pb)
                : "memory");
            bool fresh;
            if (in_neg) {
                int a = __float_as_int(u0.x) & __float_as_int(u0.y) & __float_as_int(u0.z) & __float_as_int(u0.w);
                a &= __float_as_int(u1.x) & __float_as_int(u1.y) & __float_as_int(u1.z) & __float_as_int(u1.w);
                a &= __float_as_int(u2.x) & __float_as_int(u2.y) & __float_as_int(u2.z) & __float_as_int(u2.w);
                a &= __float_as_int(u3.x) & __float_as_int(u3.y) & __float_as_int(u3.z) & __float_as_int(u3.w);
                a &= __float_as_int(u4.x) & __float_as_int(u4.y) & __float_as_int(u4.z) & __float_as_int(u4.w);
                a &= __float_as_int(u5.x) & __float_as_int(u5.y) & __float_as_int(u5.z) & __float_as_int(u5.w);
                a &= __float_as_int(u6.x) & __float_as_int(u6.y) & __float_as_int(u6.z) & __float_as_int(u6.w);
                a &= __float_as_int(u7.x) & __float_as_int(u7.y) & __float_as_int(u7.z) & __float_as_int(u7.w);
                fresh = (a < 0);                   // all sign bits set
            } else {
                int o = __float_as_int(u0.x) | __float_as_int(u0.y) | __float_as_int(u0.z) | __float_as_int(u0.w);
                o |= __float_as_int(u1.x) | __float_as_int(u1.y) | __float_as_int(u1.z) | __float_as_int(u1.w);
                o |= __float_as_int(u2.x) | __float_as_int(u2.y) | __float_as_int(u2.z) | __float_as_int(u2.w);
                o |= __float_as_int(u3.x) | __float_as_int(u3.y) | __float_as_int(u3.z) | __float_as_int(u3.w);
                o |= __float_as_int(u4.x) | __float_as_int(u4.y) | __float_as_int(u4.z) | __float_as_int(u4.w);
                o |= __float_as_int(u5.x) | __float_as_int(u5.y) | __float_as_int(u5.z) | __float_as_int(u5.w);
                o |= __float_as_int(u6.x) | __float_as_int(u6.y) | __float_as_int(u6.z) | __float_as_int(u6.w);
                o |= __float_as_int(u7.x) | __float_as_int(u7.y) | __float_as_int(u7.z) | __float_as_int(u7.w);
                fresh = (o >= 0);                  // all sign bits clear
            }
            if (__all(fresh)) break;
        }

        float m;
        m =          fmaxf(fmaxf(fabsf(u0.x), fabsf(u0.y)), fmaxf(fabsf(u0.z), fabsf(u0.w)));
        m = fmaxf(m, fmaxf(fmaxf(fabsf(u1.x), fabsf(u1.y)), fmaxf(fabsf(u1.z), fabsf(u1.w))));
        m = fmaxf(m, fmaxf(fmaxf(fabsf(u2.x), fabsf(u2.y)), fmaxf(fabsf(u2.z), fabsf(u2.w))));
        m = fmaxf(m, fmaxf(fmaxf(fabsf(u3.x), fabsf(u3.y)), fmaxf(fabsf(u3.z), fabsf(u3.w))));
        m = fmaxf(m, fmaxf(fmaxf(fabsf(u4.x), fabsf(u4.y)), fmaxf(fabsf(u4.z), fabsf(u4.w))));
        m = fmaxf(m, fmaxf(fmaxf(fabsf(u5.x), fabsf(u5.y)), fmaxf(fabsf(u5.z), fabsf(u5.w))));
        m = fmaxf(m, fmaxf(fmaxf(fabsf(u6.x), fabsf(u6.y)), fmaxf(fabsf(u6.z), fabsf(u6.w))));
        m = fmaxf(m, fmaxf(fmaxf(fabsf(u7.x), fabsf(u7.y)), fmaxf(fabsf(u7.z), fabsf(u7.w))));
        #pragma unroll
        for (int d = 1; d < 64; d <<= 1) m = fmaxf(m, __shfl_xor(m, d, 64));

        const float rn = (in_neg ? -1.0f : 1.0f) / m;
        h2f uh[16];
        uh[0]  = pk16(u0.x * rn, u0.y * rn);  uh[1]  = pk16(u0.z * rn, u0.w * rn);
        uh[2]  = pk16(u1.x * rn, u1.y * rn);  uh[3]  = pk16(u1.z * rn, u1.w * rn);
        uh[4]  = pk16(u2.x * rn, u2.y * rn);  uh[5]  = pk16(u2.z * rn, u2.w * rn);
        uh[6]  = pk16(u3.x * rn, u3.y * rn);  uh[7]  = pk16(u3.z * rn, u3.w * rn);
        uh[8]  = pk16(u4.x * rn, u4.y * rn);  uh[9]  = pk16(u4.z * rn, u4.w * rn);
        uh[10] = pk16(u5.x * rn, u5.y * rn);  uh[11] = pk16(u5.z * rn, u5.w * rn);
        uh[12] = pk16(u6.x * rn, u6.y * rn);  uh[13] = pk16(u6.z * rn, u6.w * rn);
        uh[14] = pk16(u7.x * rn, u7.y * rn);  uh[15] = pk16(u7.z * rn, u7.w * rn);
        #pragma unroll
        for (int k = 0; k < 8; ++k) {
            unsigned long long qw =
                ((unsigned long long)__builtin_bit_cast(unsigned, uh[2 * k + 1]) << 32) |
                (unsigned long long)__builtin_bit_cast(unsigned, uh[2 * k]);
            uh_dst[lane + 64 * k] = qw;
        }
        if (kept) Chat += __logf(m);
    };

    // ================= GEMV (16 rows/wave: 12 reg + 4 LDS) + store ==========
    auto GEMV_STORE = [&](const unsigned long long* uh_src, float hv0, float hv1,
                          float* u_out, int out_neg, float* save_p, float* fin_p) {
        h2f uh[16];
        #pragma unroll
        for (int k = 0; k < 8; ++k) {
            unsigned long long qw = uh_src[lane + 64 * k];
            uh[2 * k]     = __builtin_bit_cast(h2f, (unsigned)qw);
            uh[2 * k + 1] = __builtin_bit_cast(h2f, (unsigned)(qw >> 32));
        }

        // phase A: rows 0..7 (registers)
        float acc[8];
        #pragma unroll
        for (int r = 0; r < 8; ++r) acc[r] = 0.0f;
        #pragma unroll
        for (int k = 0; k < 16; ++k) {
            #pragma unroll
            for (int r = 0; r < 8; ++r)
                acc[r] = __builtin_amdgcn_fdot2(e2r[r][k], uh[k], acc[r], false);
        }
        #pragma unroll
        for (int r = 0; r < 4; ++r) {
            float send = (lane & 1) ? acc[r] : acc[r + 4];
            float recv = __shfl_xor(send, 1, 64);
            float keep = (lane & 1) ? acc[r + 4] : acc[r];
            acc[r] = keep + recv;
        }
        #pragma unroll
        for (int r = 0; r < 2; ++r) {
            float send = (lane & 2) ? acc[r] : acc[r + 2];
            float recv = __shfl_xor(send, 2, 64);
            float keep = (lane & 2) ? acc[r + 2] : acc[r];
            acc[r] = keep + recv;
        }
        {
            float send = (lane & 4) ? acc[0] : acc[1];
            float recv = __shfl_xor(send, 4, 64);
            float keep = (lane & 4) ? acc[1] : acc[0];
            acc[0] = keep + recv;
        }
        acc[0] += __shfl_xor(acc[0], 8, 64);
        acc[0] += __shfl_xor(acc[0], 16, 64);
        acc[0] += __shfl_xor(acc[0], 32, 64);
        float resA = acc[0];

        // phase B: rows 8..11 (registers) + rows 12..15 (LDS)
        #pragma unroll
        for (int r = 0; r < 8; ++r) acc[r] = 0.0f;
        #pragma unroll
        for (int k = 0; k < 8; ++k) {
            unsigned long long q0 = els64[wv * 4 + 0][lane + 64 * k];
            unsigned long long q1 = els64[wv * 4 + 1][lane + 64 * k];
            unsigned long long q2 = els64[wv * 4 + 2][lane + 64 * k];
            unsigned long long q3 = els64[wv * 4 + 3][lane + 64 * k];
            #pragma unroll
            for (int r = 0; r < 4; ++r) {
                acc[r] = __builtin_amdgcn_fdot2(e2r[8 + r][2 * k],     uh[2 * k],     acc[r], false);
                acc[r] = __builtin_amdgcn_fdot2(e2r[8 + r][2 * k + 1], uh[2 * k + 1], acc[r], false);
            }
            acc[4] = __builtin_amdgcn_fdot2(__builtin_bit_cast(h2f, (unsigned)q0),         uh[2 * k],     acc[4], false);
            acc[4] = __builtin_amdgcn_fdot2(__builtin_bit_cast(h2f, (unsigned)(q0 >> 32)), uh[2 * k + 1], acc[4], false);
            acc[5] = __builtin_amdgcn_fdot2(__builtin_bit_cast(h2f, (unsigned)q1),         uh[2 * k],     acc[5], false);
            acc[5] = __builtin_amdgcn_fdot2(__builtin_bit_cast(h2f, (unsigned)(q1 >> 32)), uh[2 * k + 1], acc[5], false);
            acc[6] = __builtin_amdgcn_fdot2(__builtin_bit_cast(h2f, (unsigned)q2),         uh[2 * k],     acc[6], false);
            acc[6] = __builtin_amdgcn_fdot2(__builtin_bit_cast(h2f, (unsigned)(q2 >> 32)), uh[2 * k + 1], acc[6], false);
            acc[7] = __builtin_amdgcn_fdot2(__builtin_bit_cast(h2f, (unsigned)q3),         uh[2 * k],     acc[7], false);
            acc[7] = __builtin_amdgcn_fdot2(__builtin_bit_cast(h2f, (unsigned)(q3 >> 32)), uh[2 * k + 1], acc[7], false);
        }
        #pragma unroll
        for (int r = 0; r < 4; ++r) {
            float send = (lane & 1) ? acc[r] : acc[r + 4];
            float recv = __shfl_xor(send, 1, 64);
            float keep = (lane & 1) ? acc[r + 4] : acc[r];
            acc[r] = keep + recv;
        }
        #pragma unroll
        for (int r = 0; r < 2; ++r) {
            float send = (lane & 2) ? acc[r] : acc[r + 2];
            float recv = __shfl_xor(send, 2, 64);
            float keep = (lane & 2) ? acc[r + 2] : acc[r];
            acc[r] = keep + recv;
        }
        {
            float send = (lane & 4) ? acc[0] : acc[1];
            float recv = __shfl_xor(send, 4, 64);
            float keep = (lane & 4) ? acc[1] : acc[0];
            acc[0] = keep + recv;
        }
        acc[0] += __shfl_xor(acc[0], 8, 64);
        acc[0] += __shfl_xor(acc[0], 16, 64);
        acc[0] += __shfl_xor(acc[0], 32, 64);
        float resB = acc[0];

        if (lane < 8) {
            float utA = resA * __expf(hv0);        // row grow
            float utB = resB * __expf(hv1);        // row grow+8
            st_coh(&u_out[grow],     out_neg ? -utA : utA);
            st_coh(&u_out[grow + 8], out_neg ? -utB : utB);
            if (save_p) { st_coh(&save_p[grow], utA); st_coh(&save_p[grow + 8], utB); }
            if (fin_p)  { st_coh(&fin_p[grow],  utA); st_coh(&fin_p[grow + 8],  utB); }
        }
    };

    // ---- prologue: uh_A <- chain A u(0)
    if (wv == 0)
        POLL_PACK(u_bufs + (ca * 2 + 0) * TSZ, 0, uh_shA, ChatA, (sA0 + 1) > skA);
    __syncthreads();

    // ================= main interleaved loop ================================
    for (int t = 0; t < TB; ++t) {
        const int sA = sA0 + t, sB = sB0 + t;
        const int outp = (t + 1) & 1, outn = ((t + 1) >> 1) & 1;
        const int inp  = t & 1,       inn  = (t >> 1) & 1;

        // prefetch emissions (plain cached loads)
        float hA0 = 0.0f, hA1 = 0.0f, hB0 = 0.0f, hB1 = 0.0f;
        if (lane < 8) {
            if (t < TA) {
                hA0 = h[(size_t)sA * TSZ + grow];
                hA1 = h[(size_t)sA * TSZ + grow + 8];
            }
            hB0 = h[(size_t)sB * TSZ + grow];
            hB1 = h[(size_t)sB * TSZ + grow + 8];
        }

        // ---- phase A: compute chain A step (uh_A holds u_A(t))
        if (t < TA) {
            GEMV_STORE(uh_shA, hA0, hA1,
                       u_bufs + (ca * 2 + outp) * TSZ, outn,
                       (ca > 0 && sA + 1 == skA) ? usave + ca * TSZ : nullptr,
                       (sA + 1 == seA) ? ufin + ca * TSZ : nullptr);
        }
        // wave1: poll chain B u(t) (stored ~1 cycle ago -> visible)
        if (wv == 1)
            POLL_PACK(u_bufs + (cb * 2 + inp) * TSZ, inn, uh_shB, ChatB,
                      (sB + 1) > skB);
        __syncthreads();

        // ---- phase B: compute chain B step (uh_B holds u_B(t))
        GEMV_STORE(uh_shB, hB0, hB1,
                   u_bufs + (cb * 2 + outp) * TSZ, outn,
                   (sB + 1 == skB) ? usave + cb * TSZ : nullptr,
                   (sB + 1 == seB) ? ufin + cb * TSZ : nullptr);
        // wave0: poll chain A u(t+1) (stored this cycle in phase A;
        // visibility hidden under phase B's GEMV)
        if (wv == 0 && (t + 1) < TA)
            POLL_PACK(u_bufs + (ca * 2 + outp) * TSZ, outn, uh_shA, ChatA,
                      (sA + 2) > skA);
        __syncthreads();
    }

    // ---- completion: store Chats, ack stores, per-wave post
    if (b == 0 && lane == 0) {
        if (wv == 0) st_coh(&cbuf[ca], ChatA);
        if (wv == 1) st_coh(&cbuf[cb], ChatB);
    }
    asm volatile("s_waitcnt vmcnt(0)" ::: "memory");
    if (lane == 0)
        __hip_atomic_store(&posts[blk * NW + wv], 1,
                           __ATOMIC_RELAXED, __HIP_MEMORY_SCOPE_AGENT);

    // ---- finisher: pair 0 / block 0 / wave 0 stitches 32 chunks
    if (cp == 0 && b == 0 && wv == 0) {
        int ok;
        do {
            __builtin_amdgcn_s_sleep(1);
            ok = 1;
            #pragma unroll
            for (int i = 0; i < 32; ++i) {     // 256 blocks x 8 waves = 2048 posts
                int v = __hip_atomic_load(&posts[lane + 64 * i],
                                          __ATOMIC_RELAXED, __HIP_MEMORY_SCOPE_AGENT);
                ok &= (v == 1);
            }
        } while (!__all(ok));

        // stitch: match log(sum u) at chunk boundaries
        float O = 0.0f;
        for (int cc = 1; cc < NCH; ++cc) {
            float sa = 0.0f, sb = 0.0f;
            for (int j = 4 * lane; j < TSZ; j += 256) {
                v4f a4 = ld_coh4(&ufin[(cc - 1) * TSZ + j]);
                v4f b4 = ld_coh4(&usave[cc * TSZ + j]);
                sa += a4.x + a4.y + a4.z + a4.w;
                sb += b4.x + b4.y + b4.z + b4.w;
            }
            #pragma unroll
            for (int d = 1; d < 64; d <<= 1) {
                sa += __shfl_xor(sa, d, 64);
                sb += __shfl_xor(sb, d, 64);
            }
            O += ld_coh1(&cbuf[cc - 1]) + __logf(sa) - __logf(sb);
        }
        // terminal: O + C_last + log(sum_j exp(T[END,j]) u_j)
        float se = 0.0f;
        for (int j = 4 * lane; j < TSZ; j += 256) {
            const float4 t4 = *(const float4*)(tr + (size_t)END_I * TSZ + j);
            v4f uf = ld_coh4(&ufin[(NCH - 1) * TSZ + j]);
            se += __expf(t4.x) * uf.x + __expf(t4.y) * uf.y +
                  __expf(t4.z) * uf.z + __expf(t4.w) * uf.w;
        }
        #pragma unroll
        for (int d = 1; d < 64; d <<= 1) se += __shfl_xor(se, d, 64);

        float ans = O + ld_coh1(&cbuf[NCH - 1]) + __logf(se);
        if (lane == 0) out[0] = ans;
    }
}

extern "C" void kernel_launch(void* const* d_in, const int* in_sizes, int n_in,
                              void* d_out, int out_size, void* d_ws, size_t ws_size,
                              hipStream_t stream) {
    const float* h  = (const float*)d_in[0];   // [8192, 2048] fp32 emissions
    const float* tr = (const float*)d_in[1];   // [2048, 2048] fp32 transitions
    (void)in_sizes; (void)n_in; (void)out_size; (void)ws_size;
    crf_chain<<<dim3(NCH / 2 * GBLK), dim3(512), 0, stream>>>(h, tr, (float*)d_out, (float*)d_ws);
}